// Round 12
// baseline (103.569 us; speedup 1.0000x reference)
//
#include <hip/hip_runtime.h>
#include <hip/hip_bf16.h>
#include <hip/hip_fp16.h>
#include <stdint.h>

typedef _Float16 f16;
typedef _Float16 f16x2 __attribute__((ext_vector_type(2)));
typedef _Float16 f16x4 __attribute__((ext_vector_type(4)));
typedef _Float16 f16x8 __attribute__((ext_vector_type(8)));
typedef float f32x4 __attribute__((ext_vector_type(4)));
typedef float f32x16 __attribute__((ext_vector_type(16)));
typedef uint32_t u32x4 __attribute__((ext_vector_type(4)));

#define B_ 4
#define QL_ 1024
#define D_ 1024
#define H_ 16
#define HD_ 64
#define KVL_ 2048
#define L2E 1.44269504088896f

// ---- async global->LDS, 16B per lane, wave-uniform LDS base ----
__device__ __forceinline__ void g2lds16(const void* g, void* l) {
    __builtin_amdgcn_global_load_lds(
        (const __attribute__((address_space(1))) uint32_t*)g,
        (__attribute__((address_space(3))) uint32_t*)l,
        16, 0, 0);
}

union U8 { uint32_t u[4]; f16x8 v; };

__device__ __forceinline__ uint32_t pkrtz(float a, float b) {
    auto t = __builtin_amdgcn_cvt_pkrtz(a, b);
    return __builtin_bit_cast(uint32_t, t);
}

// ---- Wq transpose only (gemm0 stages A from raw f32 hs itself) ----
__global__ void prep_wq(const float* __restrict__ Wq, f16* __restrict__ Wq_t) {
    __shared__ float t[64][65];
    int b2 = blockIdx.x, tid = threadIdx.x;
    int k0 = (b2 >> 4) << 6, n0 = (b2 & 15) << 6;
    int rr = tid >> 4, c4 = (tid & 15) << 2;
#pragma unroll
    for (int i = 0; i < 4; ++i) {
        int r = i * 16 + rr;
        float4 v = *(const float4*)(Wq + (size_t)(k0 + r) * 1024 + n0 + c4);
        t[r][c4 + 0] = v.x; t[r][c4 + 1] = v.y; t[r][c4 + 2] = v.z; t[r][c4 + 3] = v.w;
    }
    __syncthreads();
#pragma unroll
    for (int i = 0; i < 4; ++i) {
        int n = i * 16 + rr;
        f16x4 o;
#pragma unroll
        for (int j = 0; j < 4; ++j) o[j] = (f16)t[c4 + j][n];
        *(f16x4*)(Wq_t + (size_t)(n0 + n) * 1024 + k0 + c4) = o;
    }
}

// ---- fused: Q-proj GEMM (A from raw f32 hs) + K/V'/em/Wo prep ----
// [0,512):     GEMM  (A reg-staged f32->f16, B = Wq_t via global_load_lds)
// [512,1536):  K f32->f16 chunk-major: unit16B[(bh*32+ch)*512 + ds*128 + kv*2 + hi]
// [1536,2560): V' = V*exp(mask) f32->f16 transposed+permuted chunk-major, + em16 table
// [2560,2688): Wo transpose (2 tiles/block)
__global__ __launch_bounds__(512) void gemm0_fused(
    const float* __restrict__ hs, const f16* __restrict__ BT, f16* __restrict__ q_h,
    const float* __restrict__ K, f16* __restrict__ K_h,
    const float* __restrict__ V, f16* __restrict__ V_t,
    const float* __restrict__ Wo, f16* __restrict__ Wo_t,
    const float* __restrict__ mask, f16* __restrict__ em16) {
    __shared__ char shmem[49152];
    int bid = blockIdx.x, tid = threadIdx.x;

    if (bid < 512) {
        // ---------------- GEMM path: M=4096, N=1024, K=1024 ----------------
        char* Alds = shmem;            // [2][16384] f16, XOR-swizzled
        char* Blds = shmem + 32768;    // [2][8192]
        int xcd = bid & 7, sx = bid >> 3;
        int bm = xcd * 4 + (sx & 3);
        int bn = sx >> 2;
        int w = tid >> 6, l = tid & 63;
        int l15 = l & 15, lg = l >> 4;
        int wm = w >> 1, wn = w & 1;
        f32x4 acc[2][2] = {};

        // A: thread handles chunks i0=tid, i1=tid+512 (row +64, same swizzle)
        int rA0 = tid >> 3, c80 = tid & 7, cc0 = c80 ^ (rA0 & 7);
        const float* ags0 = hs + ((size_t)(bm * 128 + rA0) * 1024 + cc0 * 8);
        const float* ags1 = ags0 + 65536;         // +64 rows
        int aw0 = rA0 * 128 + c80 * 16;
        int aw1 = aw0 + 8192;

        int rB = w * 8 + (l >> 3);
        int ccB = (l & 7) ^ (rB & 7);
        const char* bgp = (const char*)BT + ((size_t)(bn * 64 + rB) * 1024 + ccB * 8) * 2;
        int boB = w * 1024;

        int aoff[2][2], boff[2][2];
#pragma unroll
        for (int ks = 0; ks < 2; ++ks)
#pragma unroll
            for (int m = 0; m < 2; ++m) {
                int ra = wm * 32 + m * 16 + l15;
                aoff[ks][m] = ra * 128 + ((ks * 64 + lg * 16) ^ ((ra & 7) << 4));
                int rb = wn * 32 + m * 16 + l15;
                boff[ks][m] = rb * 128 + ((ks * 64 + lg * 16) ^ ((rb & 7) << 4));
            }

        f32x4 a0, a1, a2, a3;
#define ALOAD(buf, o32, oB)                                    \
    {                                                          \
        a0 = *(const f32x4*)(ags0 + (o32));                    \
        a1 = *(const f32x4*)(ags0 + (o32) + 4);                \
        a2 = *(const f32x4*)(ags1 + (o32));                    \
        a3 = *(const f32x4*)(ags1 + (o32) + 4);                \
        g2lds16(bgp + (oB), Blds + (buf) * 8192 + boB);        \
    }
#define CVTW(buf)                                                              \
    {                                                                          \
        asm volatile("s_waitcnt vmcnt(1)" ::: "memory");                       \
        u32x4 w0 = { pkrtz(a0[0], a0[1]), pkrtz(a0[2], a0[3]),                 \
                     pkrtz(a1[0], a1[1]), pkrtz(a1[2], a1[3]) };               \
        *(u32x4*)(Alds + (buf) * 16384 + aw0) = w0;                            \
        u32x4 w1 = { pkrtz(a2[0], a2[1]), pkrtz(a2[2], a2[3]),                 \
                     pkrtz(a3[0], a3[1]), pkrtz(a3[2], a3[3]) };               \
        *(u32x4*)(Alds + (buf) * 16384 + aw1) = w1;                            \
    }
#define GCOMP(buf)                                                               \
    _Pragma("unroll") for (int ks = 0; ks < 2; ++ks) {                           \
        f16x8 af[2], bf[2];                                                      \
        af[0] = *(const f16x8*)(Alds + (buf) * 16384 + aoff[ks][0]);             \
        af[1] = *(const f16x8*)(Alds + (buf) * 16384 + aoff[ks][1]);             \
        bf[0] = *(const f16x8*)(Blds + (buf) * 8192 + boff[ks][0]);              \
        bf[1] = *(const f16x8*)(Blds + (buf) * 8192 + boff[ks][1]);              \
        _Pragma("unroll") for (int m = 0; m < 2; ++m)                            \
            _Pragma("unroll") for (int n = 0; n < 2; ++n)                        \
                acc[m][n] = __builtin_amdgcn_mfma_f32_16x16x32_f16(af[m], bf[n], acc[m][n], 0, 0, 0); \
    }
#define SYNCV()                                                          \
    {                                                                    \
        asm volatile("s_waitcnt vmcnt(0) lgkmcnt(0)" ::: "memory");      \
        __syncthreads();                                                 \
    }

        ALOAD(0, 0, 0);
        CVTW(0);
        SYNCV();
        for (int t2 = 0; t2 < 8; ++t2) {
            ALOAD(1, 64, 128);
            GCOMP(0);
            CVTW(1);
            SYNCV();
            if (t2 < 7) ALOAD(0, 128, 256);
            GCOMP(1);
            if (t2 < 7) CVTW(0);
            SYNCV();
            ags0 += 128; ags1 += 128; bgp += 256;
        }
#pragma unroll
        for (int m = 0; m < 2; ++m)
#pragma unroll
            for (int n = 0; n < 2; ++n)
#pragma unroll
                for (int i = 0; i < 4; ++i) {
                    int row = bm * 128 + wm * 32 + m * 16 + lg * 4 + i;
                    int col = bn * 64 + wn * 32 + n * 16 + l15;
                    float v = acc[m][n][i] * L2E;
                    int b = row >> 10, q = row & 1023, h = col >> 6, d = col & 63;
                    q_h[(((size_t)b * H_ + h) * QL_ + q) * HD_ + d] = (f16)v;
                }
#undef ALOAD
#undef CVTW
#undef GCOMP
#undef SYNCV
    } else if (bid < 1536) {
        // ---------------- K prep ----------------
        int t0 = (bid - 512) * 512 + tid;
#pragma unroll
        for (int rep = 0; rep < 2; ++rep) {
            int U = t0 + rep * 524288;
            int bh = U >> 14, rem = U & 16383;
            int ch = rem >> 9, r2 = rem & 511;
            int dsl = r2 >> 7, r3 = r2 & 127;
            int kv = r3 >> 1, hi2 = r3 & 1;
            const float* sp = K + (((size_t)bh * KVL_ + ch * 64 + kv) * HD_ + dsl * 16 + hi2 * 8);
            f16x8 o;
#pragma unroll
            for (int j = 0; j < 8; ++j) o[j] = (f16)sp[j];
            *(f16x8*)(K_h + (size_t)U * 8) = o;
        }
    } else if (bid < 2560) {
        // ---------------- V' prep (2 tiles/block) + em16 table ----------------
        int sub = tid >> 8, st2 = tid & 255;
        int vb = (bid - 1536) * 2 + sub;      // 0..2047
        int bh = vb >> 5, ch = vb & 31;
        int b = bh >> 4;
        float (*tt)[65] = (float(*)[65])(shmem + sub * 16640);
        float* emv = (float*)(shmem + 33280 + sub * 256);
        int rr = st2 >> 4, c4 = (st2 & 15) << 2;
#pragma unroll
        for (int i = 0; i < 4; ++i) {
            int r = i * 16 + rr;
            float4 v = *(const float4*)(V + ((size_t)bh * KVL_ + ch * 64 + r) * HD_ + c4);
            tt[r][c4 + 0] = v.x; tt[r][c4 + 1] = v.y; tt[r][c4 + 2] = v.z; tt[r][c4 + 3] = v.w;
        }
        if (st2 < 64)
            emv[st2] = __builtin_amdgcn_exp2f(mask[(size_t)b * KVL_ + ch * 64 + st2] * L2E);
        __syncthreads();
#pragma unroll
        for (int rep = 0; rep < 2; ++rep) {
            int u = st2 + rep * 256;
            int st = u >> 7, d = (u >> 1) & 63, hi2 = u & 1;
            f16x8 o;
#pragma unroll
            for (int j = 0; j < 8; ++j) {
                int kvl = st * 16 + (j & 3) + 8 * (j >> 2) + 4 * hi2;
                o[j] = (f16)(tt[kvl][d] * emv[kvl]);
            }
            *(f16x8*)(V_t + ((size_t)(bh * 32 + ch) * 512 + u) * 8) = o;
        }
        // em16[b][g32][hi][slot] = exp(mask) arranged for in-kernel pair reads
        if (((bh & 15) == 0) && st2 < 64) {
            int kb = st2 >> 5, hi2v = (st2 >> 4) & 1, slot = st2 & 15;
            int kvv = kb * 32 + (slot & 3) + 8 * (slot >> 2) + 4 * hi2v;
            em16[(((size_t)b * 64 + ch * 2 + kb) * 2 + hi2v) * 16 + slot] = (f16)emv[kvv];
        }
    } else {
        // ---------------- Wo transpose (2 tiles/block) ----------------
        int sub = tid >> 8, st2 = tid & 255;
        int b2 = (bid - 2560) * 2 + sub;      // 0..255
        float (*tt)[65] = (float(*)[65])(shmem + sub * 16640);
        int k0 = (b2 >> 4) << 6, n0 = (b2 & 15) << 6;
        int rr = st2 >> 4, c4 = (st2 & 15) << 2;
#pragma unroll
        for (int i = 0; i < 4; ++i) {
            int r = i * 16 + rr;
            float4 v = *(const float4*)(Wo + (size_t)(k0 + r) * 1024 + n0 + c4);
            tt[r][c4 + 0] = v.x; tt[r][c4 + 1] = v.y; tt[r][c4 + 2] = v.z; tt[r][c4 + 3] = v.w;
        }
        __syncthreads();
#pragma unroll
        for (int i = 0; i < 4; ++i) {
            int n = i * 16 + rr;
            f16x4 o;
#pragma unroll
            for (int j = 0; j < 4; ++j) o[j] = (f16)tt[c4 + j][n];
            *(f16x4*)(Wo_t + (size_t)(n0 + n) * 1024 + k0 + c4) = o;
        }
    }
}

// ---- GEMM1: out[M][N] = a_o[M][K] * Wo_t[N][K]^T, fp32 out ----
__global__ __launch_bounds__(512) void gemm_tn1(
    const f16* __restrict__ A, const f16* __restrict__ BT, float* __restrict__ Cout) {
    __shared__ char Alds[2][16384];
    __shared__ char Blds[2][8192];
    int d0 = blockIdx.x;
    int xcd = d0 & 7, sx = d0 >> 3;
    int bm = xcd * 4 + (sx & 3);
    int bn = sx >> 2;
    int tid = threadIdx.x, w = tid >> 6, l = tid & 63;
    int l15 = l & 15, lg = l >> 4;
    int wm = w >> 1, wn = w & 1;
    f32x4 acc[2][2] = {};

    const char* ag0; const char* ag1; int ao0, ao1;
    {
        int i0 = w, i1 = w + 8;
        int r0 = i0 * 8 + (l >> 3), r1 = i1 * 8 + (l >> 3);
        int c0 = (l & 7) ^ (r0 & 7), c1 = (l & 7) ^ (r1 & 7);
        ag0 = (const char*)A + ((size_t)(bm * 128 + r0) * 1024 + c0 * 8) * 2;
        ag1 = (const char*)A + ((size_t)(bm * 128 + r1) * 1024 + c1 * 8) * 2;
        ao0 = i0 * 1024; ao1 = i1 * 1024;
    }
    int rB = w * 8 + (l >> 3);
    int ccB = (l & 7) ^ (rB & 7);
    const char* bgp = (const char*)BT + ((size_t)(bn * 64 + rB) * 1024 + ccB * 8) * 2;
    int boB = w * 1024;

    int aoff[2][2], boff[2][2];
#pragma unroll
    for (int ks = 0; ks < 2; ++ks)
#pragma unroll
        for (int m = 0; m < 2; ++m) {
            int ra = wm * 32 + m * 16 + l15;
            aoff[ks][m] = ra * 128 + ((ks * 64 + lg * 16) ^ ((ra & 7) << 4));
            int rb = wn * 32 + m * 16 + l15;
            boff[ks][m] = rb * 128 + ((ks * 64 + lg * 16) ^ ((rb & 7) << 4));
        }
    const char* Ab = &Alds[0][0];
    const char* Bb = &Blds[0][0];

#define GSTAGE(buf, soff)                                      \
    {                                                          \
        g2lds16(ag0 + (soff), &Alds[buf][ao0]);                \
        g2lds16(ag1 + (soff), &Alds[buf][ao1]);                \
        g2lds16(bgp + (soff), &Blds[buf][boB]);                \
    }
#define GCOMP(buf)                                                               \
    _Pragma("unroll") for (int ks = 0; ks < 2; ++ks) {                           \
        f16x8 af[2], bf[2];                                                      \
        af[0] = *(const f16x8*)(Ab + (buf) * 16384 + aoff[ks][0]);               \
        af[1] = *(const f16x8*)(Ab + (buf) * 16384 + aoff[ks][1]);               \
        bf[0] = *(const f16x8*)(Bb + (buf) * 8192 + boff[ks][0]);                \
        bf[1] = *(const f16x8*)(Bb + (buf) * 8192 + boff[ks][1]);                \
        _Pragma("unroll") for (int m = 0; m < 2; ++m)                            \
            _Pragma("unroll") for (int n = 0; n < 2; ++n)                        \
                acc[m][n] = __builtin_amdgcn_mfma_f32_16x16x32_f16(af[m], bf[n], acc[m][n], 0, 0, 0); \
    }

    GSTAGE(0, 0);
    asm volatile("s_waitcnt vmcnt(0)" ::: "memory");
    __syncthreads();
    for (int t2 = 0; t2 < 8; ++t2) {
        GSTAGE(1, 128);
        GCOMP(0);
        asm volatile("s_waitcnt vmcnt(0)" ::: "memory");
        __syncthreads();
        if (t2 < 7) GSTAGE(0, 256);
        GCOMP(1);
        asm volatile("s_waitcnt vmcnt(0)" ::: "memory");
        __syncthreads();
        ag0 += 256; ag1 += 256; bgp += 256;
    }
#pragma unroll
    for (int m = 0; m < 2; ++m)
#pragma unroll
        for (int n = 0; n < 2; ++n)
#pragma unroll
            for (int i = 0; i < 4; ++i) {
                int row = bm * 128 + wm * 32 + m * 16 + lg * 4 + i;
                int col = bn * 64 + wn * 32 + n * 16 + l15;
                Cout[(size_t)row * 1024 + col] = acc[m][n][i];
            }
#undef GSTAGE
#undef GCOMP
}

// ---- fused flash attention: 4 waves/block, full kv, no merge; mask folded
// into V' and em16 (off the critical path). 4 blocks/CU (36.9KB LDS). ----
__global__ __launch_bounds__(256, 4) void attn_fused(
    const f16* __restrict__ qh, const f16* __restrict__ kh, const f16* __restrict__ vt,
    const f16* __restrict__ em16, f16* __restrict__ aout) {
    __shared__ char lds_buf[36864];  // K dbuf 16K | V dbuf 16K | em 4K
    __shared__ float frl[4][32];

    int tid = threadIdx.x, w = tid >> 6, l = tid & 63;
    int l31 = l & 31, hi = l >> 5;
    int d0 = blockIdx.x;                 // 512 blocks
    int xcd = d0 & 7, sx = d0 >> 3;
    int bh = xcd * 8 + (sx & 7);
    int qt = sx >> 3;
    int b = bh >> 4, h = bh & 15;

    const char* lbase = lds_buf + l31 * 32 + hi * 16;
    const char* embase = lds_buf + 32768 + hi * 32;

    f16x8 Qf[4];
    {
        const f16* qp = qh + ((size_t)bh * QL_ + qt * 128 + w * 32 + l31) * HD_ + hi * 8;
#pragma unroll
        for (int ds_ = 0; ds_ < 4; ++ds_) Qf[ds_] = *(const f16x8*)(qp + ds_ * 16);
    }

    // staging: 8 K-instr + 8 V-instr per 64-kv chunk over 4 waves (2+2 each)
    const char* kgp0 = (const char*)kh + ((size_t)(bh * 32) * 512 + w * 2 * 64 + l) * 16;
    const char* kgp1 = kgp0 + 1024;
    const char* vgp0 = (const char*)vt + ((size_t)(bh * 32) * 512 + w * 2 * 64 + l) * 16;
    const char* vgp1 = vgp0 + 1024;
    char* kl0 = lds_buf + w * 2048;
    char* kl1 = kl0 + 1024;
    char* vl0 = lds_buf + 16384 + w * 2048;
    char* vl1 = vl0 + 1024;

#define PREF(buf, soff)                                  \
    {                                                    \
        g2lds16(kgp0 + (soff), kl0 + (buf) * 8192);      \
        g2lds16(kgp1 + (soff), kl1 + (buf) * 8192);      \
        g2lds16(vgp0 + (soff), vl0 + (buf) * 8192);      \
        g2lds16(vgp1 + (soff), vl1 + (buf) * 8192);      \
    }

    float mrun = -1e30f, ssA = 0.f, ssB = 0.f;
    f32x16 acc[2] = {};
    int emoff = 0;   // byte offset: granule g32 -> g32*64

    // one 32-kv granule
#define BODY(buf, kb, emo)                                                                \
    {                                                                                     \
        f32x16 St = {};                                                                   \
        __builtin_amdgcn_s_setprio(1);                                                    \
        _Pragma("unroll") for (int ds_ = 0; ds_ < 4; ++ds_) {                             \
            f16x8 kf = *(const f16x8*)(lbase + (buf) * 8192 + ds_ * 2048 + (kb) * 1024);  \
            St = __builtin_amdgcn_mfma_f32_32x32x16_f16(kf, Qf[ds_], St, 0, 0, 0);        \
        }                                                                                 \
        __builtin_amdgcn_s_setprio(0);                                                    \
        float a0 = fmaxf(fmaxf(St[0], St[1]), St[2]);                                     \
        float a1 = fmaxf(fmaxf(St[3], St[4]), St[5]);                                     \
        float a2 = fmaxf(fmaxf(St[6], St[7]), St[8]);                                     \
        float a3 = fmaxf(fmaxf(St[9], St[10]), St[11]);                                   \
        float a4 = fmaxf(fmaxf(St[12], St[13]), St[14]);                                  \
        float lmax = fmaxf(fmaxf(fmaxf(a0, a1), St[15]), fmaxf(a2, fmaxf(a3, a4)));       \
        if (__any(lmax > mrun + 12.f)) {                                                  \
            float pm = fmaxf(lmax, __shfl_xor(lmax, 32));                                 \
            float mn = fmaxf(mrun, pm);                                                   \
            float fac = __builtin_amdgcn_exp2f(mrun - mn);                                \
            mrun = mn; ssA *= fac; ssB *= fac;                                            \
            frl[w][l31] = fac;                                                            \
            asm volatile("s_waitcnt lgkmcnt(0)" ::: "memory");                            \
            _Pragma("unroll") for (int g4 = 0; g4 < 4; ++g4) {                            \
                f32x4 fv = *(const f32x4*)&frl[w][g4 * 8 + hi * 4];                       \
                _Pragma("unroll") for (int c = 0; c < 2; ++c)                             \
                    _Pragma("unroll") for (int j = 0; j < 4; ++j)                         \
                        acc[c][g4 * 4 + j] *= fv[j];                                      \
            }                                                                             \
        }                                                                                 \
        uint32_t pk[8];                                                                   \
        _Pragma("unroll") for (int i = 0; i < 8; ++i) {                                   \
            float p0 = __builtin_amdgcn_exp2f(St[2 * i] - mrun);                          \
            float p1 = __builtin_amdgcn_exp2f(St[2 * i + 1] - mrun);                      \
            pk[i] = pkrtz(p0, p1);                                                        \
        }                                                                                 \
        U8 ea, eb;                                                                        \
        ea.v = *(const f16x8*)(embase + (emo));                                           \
        eb.v = *(const f16x8*)(embase + (emo) + 16);                                      \
        _Pragma("unroll") for (int i = 0; i < 4; ++i) {                                   \
            ssA = __builtin_amdgcn_fdot2(__builtin_bit_cast(f16x2, pk[2 * i]),            \
                                         __builtin_bit_cast(f16x2, (2 * i) < 4 ? ea.u[2 * i] : eb.u[2 * i - 4]), ssA, false); \
            ssB = __builtin_amdgcn_fdot2(__builtin_bit_cast(f16x2, pk[2 * i + 1]),        \
                                         __builtin_bit_cast(f16x2, (2 * i + 1) < 4 ? ea.u[2 * i + 1] : eb.u[2 * i - 3]), ssB, false); \
        }                                                                                 \
        __builtin_amdgcn_s_setprio(1);                                                    \
        _Pragma("unroll") for (int sti = 0; sti < 2; ++sti) {                             \
            U8 pa;                                                                        \
            pa.u[0] = pk[sti * 4 + 0]; pa.u[1] = pk[sti * 4 + 1];                         \
            pa.u[2] = pk[sti * 4 + 2]; pa.u[3] = pk[sti * 4 + 3];                         \
            const int st_ = (kb) * 2 + sti;                                               \
            _Pragma("unroll") for (int c = 0; c < 2; ++c) {                               \
                U8 vb;                                                                    \
                vb.v = *(const f16x8*)(lbase + 16384 + (buf) * 8192 + st_ * 2048 + c * 1024); \
                acc[c] = __builtin_amdgcn_mfma_f32_32x32x16_f16(pa.v, vb.v, acc[c], 0, 0, 0); \
            }                                                                             \
        }                                                                                 \
        __builtin_amdgcn_s_setprio(0);                                                    \
    }

    // stage em table (4KB over 4 waves) + first K/V chunk
    g2lds16((const char*)em16 + b * 4096 + w * 1024 + l * 16, lds_buf + 32768 + w * 1024);
    PREF(0, 0);
    asm volatile("s_waitcnt vmcnt(0)" ::: "memory");
    __syncthreads();

    for (int it = 0; it < 16; ++it) {
        PREF(1, 8192);
        BODY(0, 0, emoff);
        BODY(0, 1, emoff + 64);
        asm volatile("s_waitcnt vmcnt(0)" ::: "memory");
        __syncthreads();
        if (it < 15) PREF(0, 16384);
        BODY(1, 0, emoff + 128);
        BODY(1, 1, emoff + 192);
        asm volatile("s_waitcnt vmcnt(0)" ::: "memory");
        __syncthreads();
        kgp0 += 16384; kgp1 += 16384; vgp0 += 16384; vgp1 += 16384;
        emoff += 256;
    }

    // ---- epilogue: normalize and store (no merge needed) ----
    float ssum = ssA + ssB;
    ssum += __shfl_xor(ssum, 32);
    float rinv = 1.0f / ssum;
    frl[w][l31] = rinv;
    asm volatile("s_waitcnt lgkmcnt(0)" ::: "memory");
#pragma unroll
    for (int g4 = 0; g4 < 4; ++g4) {
        f32x4 rv = *(const f32x4*)&frl[w][g4 * 8 + hi * 4];
#pragma unroll
        for (int c = 0; c < 2; ++c)
#pragma unroll
            for (int j = 0; j < 4; ++j) {
                float o = acc[c][g4 * 4 + j] * rv[j];
                int q = qt * 128 + w * 32 + g4 * 8 + hi * 4 + j;
                int dd = c * 32 + l31;
                aout[((size_t)b * QL_ + q) * D_ + h * HD_ + dd] = (f16)o;
            }
    }
#undef PREF
#undef BODY
}

extern "C" void kernel_launch(void* const* d_in, const int* in_sizes, int n_in,
                              void* d_out, int out_size, void* d_ws, size_t ws_size,
                              hipStream_t stream) {
    const float* hs = (const float*)d_in[0];
    const float* K  = (const float*)d_in[1];
    const float* V  = (const float*)d_in[2];
    const float* mask = (const float*)d_in[3];
    const float* Wq = (const float*)d_in[4];
    const float* Wo = (const float*)d_in[5];
    float* out = (float*)d_out;
    char* ws = (char*)d_ws;

    f16* Wq_t = (f16*)(ws + 0);           //  2 MB
    f16* Wo_t = (f16*)(ws + 2097152);     //  2 MB
    f16* K_h  = (f16*)(ws + 4194304);     // 16 MB, chunk-major
    f16* V_t  = (f16*)(ws + 20971520);    // 16 MB, chunk-major, mask-folded
    f16* q_h  = (f16*)(ws + 37748736);    //  8 MB (b,h,q,d), pre-scaled by log2e
    f16* a_o  = (f16*)(ws + 46137344);    //  8 MB (b,q,h*64+d)
    f16* em16 = (f16*)(ws + 54525952);    // 16 KB exp(mask) pair table

    prep_wq<<<256, 256, 0, stream>>>(Wq, Wq_t);
    gemm0_fused<<<2688, 512, 0, stream>>>(hs, Wq_t, q_h, K, K_h, V, V_t,
                                          Wo, Wo_t, mask, em16);
    attn_fused<<<512, 256, 0, stream>>>(q_h, K_h, V_t, em16, a_o);
    gemm_tn1<<<512, 512, 0, stream>>>(a_o, Wo_t, out);
}